// Round 23
// baseline (495.884 us; speedup 1.0000x reference)
//
#include <hip/hip_runtime.h>

#define SENT 0xFFFFFFFFu
#define BIN_SHIFT 10
#define BIN_W (1 << BIN_SHIFT)
#define MAXBIN 2048   // supports N up to 2M (packing needs N <= 2^18)
#define CAP 36864     // fixed per-bin temp capacity (max expected ~31.3k)
#define VMASK 0x3FFFFu
#define M28 0x0FFFFFFFu
#define DUPBIT 0x80000000u

// ---------------- tables ----------------
__constant__ int c_tri[16][6] = {
 {-1,-1,-1,-1,-1,-1},{1,0,2,-1,-1,-1},{4,0,3,-1,-1,-1},{1,4,2,1,3,4},
 {3,1,5,-1,-1,-1},{2,3,0,2,5,3},{1,4,0,1,5,4},{4,2,5,-1,-1,-1},
 {4,5,2,-1,-1,-1},{4,1,0,4,5,1},{3,2,0,3,5,2},{1,3,5,-1,-1,-1},
 {4,1,2,4,3,1},{3,0,4,-1,-1,-1},{2,0,1,-1,-1,-1},{-1,-1,-1,-1,-1,-1}};
__constant__ int c_ntri[16] = {0,1,1,2,1,2,2,1,1,2,2,1,2,1,1,0};
__constant__ int c_ea[6] = {0,0,0,1,1,2};
__constant__ int c_eb[6] = {1,2,3,2,3,3};

// ---------------- utility ----------------
// init fixed-cap cursors: gcursor[b] = b*CAP
__global__ void k_init_cursor(unsigned* gcursor, int nbin) {
    int i = blockIdx.x * blockDim.x + threadIdx.x;
    if (i < nbin) gcursor[i] = (unsigned)i * CAP;
}

__global__ void k_zero_pad(const unsigned* __restrict__ total,
                           float* __restrict__ verts, float* __restrict__ vvalid, int nv) {
    int r = blockIdx.x * blockDim.x + threadIdx.x;
    if (r >= nv) return;
    unsigned V = *total;
    if ((unsigned)r < V) return;
    size_t b = (size_t)r * 3;
    verts[b + 0] = 0.f;
    verts[b + 1] = 0.f;
    verts[b + 2] = 0.f;
    vvalid[r] = 0.f;
}

// ---------------- scan (exclusive, n -> out[n+1]) ----------------
#define SBS 256
#define SIT 4

__global__ void k_scan1(const unsigned* in, unsigned* out, unsigned* bsum, int n) {
    __shared__ unsigned sm[SBS];
    int t = threadIdx.x, blk = blockIdx.x;
    int base = blk * SBS * SIT + t * SIT;
    unsigned v[SIT];
    unsigned tot = 0;
#pragma unroll
    for (int k = 0; k < SIT; k++) {
        v[k] = (base + k < n) ? in[base + k] : 0u;
        tot += v[k];
    }
    sm[t] = tot;
    __syncthreads();
    for (int off = 1; off < SBS; off <<= 1) {
        unsigned x = (t >= off) ? sm[t - off] : 0u;
        __syncthreads();
        sm[t] += x;
        __syncthreads();
    }
    unsigned run = (t == 0) ? 0u : sm[t - 1];
#pragma unroll
    for (int k = 0; k < SIT; k++) {
        if (base + k < n) out[base + k] = run;
        run += v[k];
    }
    if (t == SBS - 1) bsum[blk] = sm[SBS - 1];
}

__global__ void k_scan2(unsigned* bsum, unsigned* out, int nb, int n) {
    __shared__ unsigned sm[SBS];
    int t = threadIdx.x;
    int k = (nb + SBS - 1) / SBS;
    int st = t * k, en = min(st + k, nb);
    unsigned loc = 0;
    for (int i = st; i < en; i++) loc += bsum[i];
    sm[t] = loc;
    __syncthreads();
    for (int off = 1; off < SBS; off <<= 1) {
        unsigned x = (t >= off) ? sm[t - off] : 0u;
        __syncthreads();
        sm[t] += x;
        __syncthreads();
    }
    unsigned run = (t == 0) ? 0u : sm[t - 1];
    for (int i = st; i < en; i++) {
        unsigned tmp = bsum[i];
        bsum[i] = run;
        run += tmp;
    }
    if (t == SBS - 1) out[n] = run;  // grand total
}

__global__ void k_scan3(unsigned* out, const unsigned* bsum, int n) {
    int t = threadIdx.x, blk = blockIdx.x;
    int base = blk * SBS * SIT + t * SIT;
    unsigned add = bsum[blk];
#pragma unroll
    for (int k = 0; k < SIT; k++) {
        if (base + k < n) out[base + k] += add;
    }
}

// ---------------- pipeline ----------------
// single-pass: tcode + LDS bin count + fixed-cap chunk reservation + scatter
__global__ void k_binscatter2(const int* __restrict__ tet, const float* __restrict__ sdf,
                              unsigned char* __restrict__ tcode,
                              unsigned* __restrict__ gcursor,
                              unsigned* __restrict__ temp_pk,
                              unsigned* __restrict__ eidx, int F, int nbin) {
    __shared__ unsigned s_cnt[MAXBIN];
    __shared__ unsigned s_base[MAXBIN];
    int tid = threadIdx.x;
    for (int i = tid; i < nbin; i += blockDim.x) s_cnt[i] = 0;
    __syncthreads();

    int base = blockIdx.x * (int)blockDim.x * 4;
    int4 tv[4];
    int code[4];
#pragma unroll
    for (int k = 0; k < 4; k++) {
        int f = base + k * (int)blockDim.x + tid;
        code[k] = 0;
        if (f < F) {
            int4 t4 = ((const int4*)tet)[f];
            int c = 0;
            c |= (sdf[t4.x] > 0.f) ? 1 : 0;
            c |= (sdf[t4.y] > 0.f) ? 2 : 0;
            c |= (sdf[t4.z] > 0.f) ? 4 : 0;
            c |= (sdf[t4.w] > 0.f) ? 8 : 0;
            tcode[f] = (unsigned char)c;
            if (c != 0 && c != 15) {
                code[k] = c;
                tv[k] = t4;
            }
        }
    }
#pragma unroll
    for (int k = 0; k < 4; k++) {
        if (!code[k]) continue;
        int v[4] = {tv[k].x, tv[k].y, tv[k].z, tv[k].w};
#pragma unroll
        for (int j = 0; j < 6; j++) {
            int i0 = c_ea[j], i1 = c_eb[j];
            if (((code[k] >> i0) & 1) != ((code[k] >> i1) & 1)) {
                int a = min(v[i0], v[i1]);
                atomicAdd(&s_cnt[a >> BIN_SHIFT], 1u);
            }
        }
    }
    __syncthreads();
    for (int i = tid; i < nbin; i += blockDim.x) {
        unsigned c = s_cnt[i];
        s_base[i] = c ? atomicAdd(&gcursor[i], c) : 0u;
        s_cnt[i] = 0;
    }
    __syncthreads();
#pragma unroll
    for (int k = 0; k < 4; k++) {
        if (!code[k]) continue;
        int f = base + k * (int)blockDim.x + tid;
        int v[4] = {tv[k].x, tv[k].y, tv[k].z, tv[k].w};
#pragma unroll
        for (int j = 0; j < 6; j++) {
            int i0 = c_ea[j], i1 = c_eb[j];
            if (((code[k] >> i0) & 1) != ((code[k] >> i1) & 1)) {
                int a = min(v[i0], v[i1]);
                int b = max(v[i0], v[i1]);
                int bin = a >> BIN_SHIFT;
                unsigned pos = s_base[bin] + atomicAdd(&s_cnt[bin], 1u);
                temp_pk[pos] = ((unsigned)(a & (BIN_W - 1)) << 18) | (unsigned)b;
                eidx[f * 6 + j] = pos;   // fixed-cap temp index
            }
        }
    }
}

// derive per-bin counts from cursors (count = gcursor[b] - b*CAP), scan -> bin_base
__global__ void k_scan_bins2(const unsigned* __restrict__ gcursor,
                             unsigned* __restrict__ bin_base, int nbin) {
    __shared__ unsigned sm[SBS];
    int t = threadIdx.x;
    int k = (nbin + SBS - 1) / SBS;
    int st = t * k, en = min(st + k, nbin);
    unsigned loc = 0;
    for (int i = st; i < en; i++) loc += gcursor[i] - (unsigned)i * CAP;
    sm[t] = loc;
    __syncthreads();
    for (int off = 1; off < SBS; off <<= 1) {
        unsigned x = (t >= off) ? sm[t - off] : 0u;
        __syncthreads();
        sm[t] += x;
        __syncthreads();
    }
    unsigned run = (t == 0) ? 0u : sm[t - 1];
    for (int i = st; i < en; i++) {
        bin_base[i] = run;
        run += gcursor[i] - (unsigned)i * CAP;
    }
    if (t == SBS - 1) bin_base[nbin] = run;
}

// level 2 (fused): block per bin, 1024 threads.
//   phase 1: per-a counts in LDS + scan -> coalesced scat_base write
//   phase 2: compact pool_b scatter + tpos record
//   phase 3 (fused markdup): own-element dup marking, span bases from LDS
//   phase 4 (fused cnt): per-a distinct count -> cnt[a] (covers empty a too)
__global__ __launch_bounds__(1024)
void k_fine3(const unsigned* __restrict__ bin_base,
             const unsigned* __restrict__ temp_pk,
             unsigned* __restrict__ pool_b,
             unsigned* __restrict__ tpos,
             unsigned* __restrict__ scat_base,
             unsigned* __restrict__ cnt, int N, int nbin) {
    __shared__ unsigned s_cnt[BIN_W];
    __shared__ unsigned s_scan[BIN_W];
    int bin = blockIdx.x;
    int tid = threadIdx.x;  // 0..1023
    int a0 = bin << BIN_SHIFT;
    int w = min(BIN_W, N - a0);
    unsigned start = bin_base[bin];
    unsigned cnt_bin = bin_base[bin + 1] - start;
    unsigned tstart = (unsigned)bin * CAP;
    s_cnt[tid] = 0;
    __syncthreads();
    for (unsigned i = tid; i < cnt_bin; i += 1024)
        atomicAdd(&s_cnt[temp_pk[tstart + i] >> 18], 1u);
    __syncthreads();
    unsigned c = s_cnt[tid];
    s_scan[tid] = c;
    __syncthreads();
    for (int off = 1; off < BIN_W; off <<= 1) {
        unsigned x = (tid >= off) ? s_scan[tid - off] : 0u;
        __syncthreads();
        s_scan[tid] += x;
        __syncthreads();
    }
    unsigned base = start + s_scan[tid] - c;  // exclusive
    if (tid < w) scat_base[a0 + tid] = base;
    s_cnt[tid] = base;                        // cursor
    if (bin == nbin - 1 && tid == 0) scat_base[N] = bin_base[nbin];
    __syncthreads();
    for (unsigned i = tid; i < cnt_bin; i += 1024) {
        unsigned idx = tstart + i;
        unsigned t = temp_pk[idx];
        unsigned pos = atomicAdd(&s_cnt[t >> 18], 1u);
        pool_b[pos] = t & M28;
        tpos[pos] = idx;   // pool pos -> fixed-cap temp idx
    }
    __syncthreads();  // drains vmcnt: block's pool writes visible to block
    // phase 3: dup marking (own-element write; readers mask M28)
    for (unsigned i = tid; i < cnt_bin; i += 1024) {
        unsigned pp = start + i;
        unsigned p = pool_b[pp] & M28;
        unsigned al = p >> 18;
        unsigned s = start + (al ? s_scan[al - 1] : 0u);
        bool dup = false;
        for (unsigned j = s; j < pp; j++) {
            if ((pool_b[j] & M28) == p) { dup = true; break; }
        }
        if (dup) pool_b[pp] = p | DUPBIT;
    }
    __syncthreads();  // dup marks visible
    // phase 4: per-a distinct count (also zeroes empty buckets)
    if (tid < w) {
        unsigned s = start + (tid ? s_scan[tid - 1] : 0u);
        unsigned e = start + s_scan[tid];
        int d = 0;
        for (unsigned j = s; j < e; j++) d += (pool_b[j] & DUPBIT) ? 0 : 1;
        cnt[a0 + tid] = (unsigned)d;
    }
}

// ---- element-parallel rank ----

__device__ __forceinline__ int find_bin(const unsigned* __restrict__ bin_base,
                                        unsigned idx, int nbin) {
    int lo = 0, hi = nbin - 1;
    while (lo < hi) {
        int mid = (lo + hi + 1) >> 1;
        if (bin_base[mid] <= idx) lo = mid;
        else hi = mid - 1;
    }
    return lo;
}

// distinct-rank via span count. Writes:
//   rank8[tpos[idx]] = r   pool_sorted[s+r] = b (non-dups)
__global__ void k_rankem(const unsigned* __restrict__ bin_base,
                         const unsigned* __restrict__ scat_base,
                         const unsigned* __restrict__ pool_b,
                         const unsigned* __restrict__ tpos,
                         unsigned* __restrict__ pool_sorted,
                         unsigned char* __restrict__ rank8, int nbin) {
    unsigned total = bin_base[nbin];
    unsigned idx = blockIdx.x * 256u + threadIdx.x;
    if (idx >= total) return;
    int bin = find_bin(bin_base, idx, nbin);
    unsigned p = pool_b[idx];
    unsigned pm = p & M28;
    unsigned a = ((unsigned)bin << BIN_SHIFT) + (pm >> 18);
    unsigned s = scat_base[a];
    unsigned e = scat_base[a + 1];
    int r = 0;
    for (unsigned j = s; j < e; j++) {
        unsigned q = pool_b[j];
        r += (!(q & DUPBIT) && (q & M28) < pm) ? 1 : 0;
    }
    rank8[tpos[idx]] = (unsigned char)r;
    if (!(p & DUPBIT)) pool_sorted[s + r] = pm & VMASK;  // b only
}

// wave-per-bucket vert writer
__global__ void k_verts(const float* __restrict__ pos, const float* __restrict__ sdf,
                        const unsigned* __restrict__ scat_base, const unsigned* __restrict__ cnt,
                        const unsigned* __restrict__ rank_base, const unsigned* __restrict__ pool_sorted,
                        float* __restrict__ verts, float* __restrict__ vvalid, int N) {
    int a = (int)((blockIdx.x * blockDim.x + threadIdx.x) >> 6);
    int lane = threadIdx.x & 63;
    if (a >= N) return;
    int d = (int)cnt[a];
    if (d == 0) return;
    unsigned s = scat_base[a];
    unsigned rb = rank_base[a];
    float sa = sdf[a];
    float pax = pos[(size_t)a * 3 + 0];
    float pay = pos[(size_t)a * 3 + 1];
    float paz = pos[(size_t)a * 3 + 2];
    for (int i = lane; i < d; i += 64) {
        unsigned b = pool_sorted[s + i];
        float sbv = sdf[b];
        float denom = sa - sbv;
        float w0 = (-sbv) / denom;
        float w1 = sa / denom;
        size_t r = (size_t)(rb + i);
        verts[r * 3 + 0] = pax * w0 + pos[(size_t)b * 3 + 0] * w1;
        verts[r * 3 + 1] = pay * w0 + pos[(size_t)b * 3 + 1] * w1;
        verts[r * 3 + 2] = paz * w0 + pos[(size_t)b * 3 + 2] * w1;
        vvalid[r] = 1.0f;
    }
}

// faces: rank = rank_base[A] + rank8[eidx[...]] (direct byte gather)
__global__ void k_faces(const int* __restrict__ tet, const unsigned char* __restrict__ tcode,
                        const unsigned* __restrict__ eidx,
                        const unsigned* __restrict__ rank_base,
                        const unsigned char* __restrict__ rank8,
                        float* __restrict__ faces, float* __restrict__ fvalid, int F) {
    int f = blockIdx.x * blockDim.x + threadIdx.x;
    if (f >= F) return;
    int code = tcode[f];
    int nt = c_ntri[code];
    size_t r0 = (size_t)f * 3;
    size_t r1 = ((size_t)F + f) * 3;
    if (nt == 0) {
        faces[r0 + 0] = -1.f; faces[r0 + 1] = -1.f; faces[r0 + 2] = -1.f;
        faces[r1 + 0] = -1.f; faces[r1 + 1] = -1.f; faces[r1 + 2] = -1.f;
        fvalid[f] = 0.f;
        fvalid[F + f] = 0.f;
        return;
    }
    int4 tv = ((const int4*)tet)[f];
    int v[4] = {tv.x, tv.y, tv.z, tv.w};
    float rk[6];
#pragma unroll
    for (int j = 0; j < 6; j++) {
        int i0 = c_ea[j], i1 = c_eb[j];
        if (((code >> i0) & 1) != ((code >> i1) & 1)) {
            int A = min(v[i0], v[i1]);
            rk[j] = (float)(rank_base[A] + (unsigned)rank8[eidx[f * 6 + j]]);
        }
    }
    float f0[3], f1[3] = {-1.f, -1.f, -1.f};
#pragma unroll
    for (int k = 0; k < 3; k++) f0[k] = rk[c_tri[code][k]];
    if (nt == 2) {
#pragma unroll
        for (int k = 0; k < 3; k++) f1[k] = rk[c_tri[code][3 + k]];
    }
    faces[r0 + 0] = f0[0]; faces[r0 + 1] = f0[1]; faces[r0 + 2] = f0[2];
    faces[r1 + 0] = f1[0]; faces[r1 + 1] = f1[1]; faces[r1 + 2] = f1[2];
    fvalid[f] = 1.f;
    fvalid[F + f] = (nt == 2) ? 1.f : 0.f;
}

// ---------------- host launch ----------------
static void run_scan(const unsigned* in, unsigned* out, unsigned* bsum,
                     int n, hipStream_t stream) {
    int nb = (n + SBS * SIT - 1) / (SBS * SIT);
    k_scan1<<<nb, SBS, 0, stream>>>(in, out, bsum, n);
    k_scan2<<<1, SBS, 0, stream>>>(bsum, out, nb, n);
    k_scan3<<<nb, SBS, 0, stream>>>(out, bsum, n);
}

extern "C" void kernel_launch(void* const* d_in, const int* in_sizes, int n_in,
                              void* d_out, int out_size, void* d_ws, size_t ws_size,
                              hipStream_t stream) {
    const float* pos = (const float*)d_in[0];
    const float* sdf = (const float*)d_in[1];
    const int* tet = (const int*)d_in[2];
    const int N = in_sizes[1];
    const int F = in_sizes[2] / 4;
    const int E = F * 6;
    const int nbin = (N + BIN_W - 1) >> BIN_SHIFT;
    const size_t tempw = (size_t)nbin * CAP;

    float* out = (float*)d_out;
    size_t nverts = (size_t)6 * F;
    size_t nfaces = (size_t)2 * F;
    float* o_verts = out;                    // [6F,3]
    float* o_faces = out + nverts * 3;       // [2F,3]
    float* o_vvalid = o_faces + nfaces * 3;  // [6F]
    float* o_fvalid = o_vvalid + nverts;     // [2F]

    unsigned* w = (unsigned*)d_ws;
    unsigned* scat_base = w;                  // N+1
    unsigned* cnt = scat_base + N + 1;        // N (fully written by k_fine3)
    unsigned* rank_base = cnt + N;            // N+1
    unsigned* bsum = rank_base + N + 1;       // 4096
    unsigned* bin_base = bsum + 4096;         // MAXBIN+1
    unsigned* gcursor = bin_base + MAXBIN + 1;// MAXBIN
    unsigned* pool_b = gcursor + MAXBIN;      // E
    unsigned* pool_sorted = pool_b + E;       // E
    unsigned* eidx = pool_sorted + E;         // E
    unsigned* tpos = eidx + E;                // E
    unsigned* temp_pk = tpos + E;             // nbin*CAP
    unsigned char* rank8 = (unsigned char*)(temp_pk + tempw);  // nbin*CAP bytes
    unsigned char* tcode = rank8 + tempw;                      // F bytes

    const int BS = 256;
    int gF = (F + BS - 1) / BS;
    int gW = (N + 3) / 4;        // wave-per-bucket blocks (k_verts)
    int gE = (E + BS - 1) / BS;  // element-parallel blocks (upper bound)
    int gV = (int)((nverts + BS - 1) / BS);
    int gB = (F + BS * 4 - 1) / (BS * 4);

    // 1. init fixed-cap cursors
    k_init_cursor<<<(nbin + BS - 1) / BS, BS, 0, stream>>>(gcursor, nbin);

    // 2. single-pass tcode + binned scatter (fixed-cap regions)
    k_binscatter2<<<gB, BS, 0, stream>>>(tet, sdf, tcode, gcursor, temp_pk, eidx, F, nbin);

    // 3. counts from cursors -> bin_base
    k_scan_bins2<<<1, SBS, 0, stream>>>(gcursor, bin_base, nbin);

    // 4. fused fine scatter + dup-mark + per-a distinct counts
    k_fine3<<<nbin, 1024, 0, stream>>>(bin_base, temp_pk, pool_b, tpos,
                                       scat_base, cnt, N, nbin);

    // 5. element-parallel rank
    k_rankem<<<gE, BS, 0, stream>>>(bin_base, scat_base, pool_b, tpos,
                                    pool_sorted, rank8, nbin);

    // 6. scan distinct counts -> global vert ranks
    run_scan(cnt, rank_base, bsum, N, stream);

    // 7. zero only padded vert rows
    k_zero_pad<<<gV, BS, 0, stream>>>(rank_base + N, o_verts, o_vvalid, (int)nverts);

    // 8. verts
    k_verts<<<gW, BS, 0, stream>>>(pos, sdf, scat_base, cnt, rank_base, pool_sorted,
                                   o_verts, o_vvalid, N);

    // 9. faces
    k_faces<<<gF, BS, 0, stream>>>(tet, tcode, eidx, rank_base, rank8,
                                   o_faces, o_fvalid, F);
}

// Round 24
// 341.436 us; speedup vs baseline: 1.4523x; 1.4523x over previous
//
#include <hip/hip_runtime.h>

#define SENT 0xFFFFFFFFu
#define BIN_SHIFT 10
#define BIN_W (1 << BIN_SHIFT)
#define MAXBIN 2048   // supports N up to 2M (packing needs N <= 2^18)
#define CAP 36864     // fixed per-bin temp capacity (max expected ~31.3k)
#define VMASK 0x3FFFFu
#define M28 0x0FFFFFFFu
#define DUPBIT 0x80000000u

// ---------------- tables ----------------
__constant__ int c_tri[16][6] = {
 {-1,-1,-1,-1,-1,-1},{1,0,2,-1,-1,-1},{4,0,3,-1,-1,-1},{1,4,2,1,3,4},
 {3,1,5,-1,-1,-1},{2,3,0,2,5,3},{1,4,0,1,5,4},{4,2,5,-1,-1,-1},
 {4,5,2,-1,-1,-1},{4,1,0,4,5,1},{3,2,0,3,5,2},{1,3,5,-1,-1,-1},
 {4,1,2,4,3,1},{3,0,4,-1,-1,-1},{2,0,1,-1,-1,-1},{-1,-1,-1,-1,-1,-1}};
__constant__ int c_ntri[16] = {0,1,1,2,1,2,2,1,1,2,2,1,2,1,1,0};
__constant__ int c_ea[6] = {0,0,0,1,1,2};
__constant__ int c_eb[6] = {1,2,3,2,3,3};

// ---------------- utility ----------------
__global__ void k_zero_u32(unsigned* p, int n) {
    int i = blockIdx.x * blockDim.x + threadIdx.x;
    int st = gridDim.x * blockDim.x;
    for (; i < n; i += st) p[i] = 0u;
}

// init fixed-cap cursors: gcursor[b] = b*CAP
__global__ void k_init_cursor(unsigned* gcursor, int nbin) {
    int i = blockIdx.x * blockDim.x + threadIdx.x;
    if (i < nbin) gcursor[i] = (unsigned)i * CAP;
}

__global__ void k_zero_pad(const unsigned* __restrict__ total,
                           float* __restrict__ verts, float* __restrict__ vvalid, int nv) {
    int r = blockIdx.x * blockDim.x + threadIdx.x;
    if (r >= nv) return;
    unsigned V = *total;
    if ((unsigned)r < V) return;
    size_t b = (size_t)r * 3;
    verts[b + 0] = 0.f;
    verts[b + 1] = 0.f;
    verts[b + 2] = 0.f;
    vvalid[r] = 0.f;
}

// ---------------- scan (exclusive, n -> out[n+1]) ----------------
#define SBS 256
#define SIT 4

__global__ void k_scan1(const unsigned* in, unsigned* out, unsigned* bsum, int n) {
    __shared__ unsigned sm[SBS];
    int t = threadIdx.x, blk = blockIdx.x;
    int base = blk * SBS * SIT + t * SIT;
    unsigned v[SIT];
    unsigned tot = 0;
#pragma unroll
    for (int k = 0; k < SIT; k++) {
        v[k] = (base + k < n) ? in[base + k] : 0u;
        tot += v[k];
    }
    sm[t] = tot;
    __syncthreads();
    for (int off = 1; off < SBS; off <<= 1) {
        unsigned x = (t >= off) ? sm[t - off] : 0u;
        __syncthreads();
        sm[t] += x;
        __syncthreads();
    }
    unsigned run = (t == 0) ? 0u : sm[t - 1];
#pragma unroll
    for (int k = 0; k < SIT; k++) {
        if (base + k < n) out[base + k] = run;
        run += v[k];
    }
    if (t == SBS - 1) bsum[blk] = sm[SBS - 1];
}

__global__ void k_scan2(unsigned* bsum, unsigned* out, int nb, int n) {
    __shared__ unsigned sm[SBS];
    int t = threadIdx.x;
    int k = (nb + SBS - 1) / SBS;
    int st = t * k, en = min(st + k, nb);
    unsigned loc = 0;
    for (int i = st; i < en; i++) loc += bsum[i];
    sm[t] = loc;
    __syncthreads();
    for (int off = 1; off < SBS; off <<= 1) {
        unsigned x = (t >= off) ? sm[t - off] : 0u;
        __syncthreads();
        sm[t] += x;
        __syncthreads();
    }
    unsigned run = (t == 0) ? 0u : sm[t - 1];
    for (int i = st; i < en; i++) {
        unsigned tmp = bsum[i];
        bsum[i] = run;
        run += tmp;
    }
    if (t == SBS - 1) out[n] = run;  // grand total
}

__global__ void k_scan3(unsigned* out, const unsigned* bsum, int n) {
    int t = threadIdx.x, blk = blockIdx.x;
    int base = blk * SBS * SIT + t * SIT;
    unsigned add = bsum[blk];
#pragma unroll
    for (int k = 0; k < SIT; k++) {
        if (base + k < n) out[base + k] += add;
    }
}

// ---------------- pipeline ----------------
// single-pass: tcode + LDS bin count + fixed-cap chunk reservation + scatter
__global__ void k_binscatter2(const int* __restrict__ tet, const float* __restrict__ sdf,
                              unsigned char* __restrict__ tcode,
                              unsigned* __restrict__ gcursor,
                              unsigned* __restrict__ temp_pk,
                              unsigned* __restrict__ eidx, int F, int nbin) {
    __shared__ unsigned s_cnt[MAXBIN];
    __shared__ unsigned s_base[MAXBIN];
    int tid = threadIdx.x;
    for (int i = tid; i < nbin; i += blockDim.x) s_cnt[i] = 0;
    __syncthreads();

    int base = blockIdx.x * (int)blockDim.x * 4;
    int4 tv[4];
    int code[4];
#pragma unroll
    for (int k = 0; k < 4; k++) {
        int f = base + k * (int)blockDim.x + tid;
        code[k] = 0;
        if (f < F) {
            int4 t4 = ((const int4*)tet)[f];
            int c = 0;
            c |= (sdf[t4.x] > 0.f) ? 1 : 0;
            c |= (sdf[t4.y] > 0.f) ? 2 : 0;
            c |= (sdf[t4.z] > 0.f) ? 4 : 0;
            c |= (sdf[t4.w] > 0.f) ? 8 : 0;
            tcode[f] = (unsigned char)c;
            if (c != 0 && c != 15) {
                code[k] = c;
                tv[k] = t4;
            }
        }
    }
#pragma unroll
    for (int k = 0; k < 4; k++) {
        if (!code[k]) continue;
        int v[4] = {tv[k].x, tv[k].y, tv[k].z, tv[k].w};
#pragma unroll
        for (int j = 0; j < 6; j++) {
            int i0 = c_ea[j], i1 = c_eb[j];
            if (((code[k] >> i0) & 1) != ((code[k] >> i1) & 1)) {
                int a = min(v[i0], v[i1]);
                atomicAdd(&s_cnt[a >> BIN_SHIFT], 1u);
            }
        }
    }
    __syncthreads();
    for (int i = tid; i < nbin; i += blockDim.x) {
        unsigned c = s_cnt[i];
        s_base[i] = c ? atomicAdd(&gcursor[i], c) : 0u;
        s_cnt[i] = 0;
    }
    __syncthreads();
#pragma unroll
    for (int k = 0; k < 4; k++) {
        if (!code[k]) continue;
        int f = base + k * (int)blockDim.x + tid;
        int v[4] = {tv[k].x, tv[k].y, tv[k].z, tv[k].w};
#pragma unroll
        for (int j = 0; j < 6; j++) {
            int i0 = c_ea[j], i1 = c_eb[j];
            if (((code[k] >> i0) & 1) != ((code[k] >> i1) & 1)) {
                int a = min(v[i0], v[i1]);
                int b = max(v[i0], v[i1]);
                int bin = a >> BIN_SHIFT;
                unsigned pos = s_base[bin] + atomicAdd(&s_cnt[bin], 1u);
                temp_pk[pos] = ((unsigned)(a & (BIN_W - 1)) << 18) | (unsigned)b;
                eidx[f * 6 + j] = pos;   // fixed-cap temp index
            }
        }
    }
}

// derive per-bin counts from cursors (count = gcursor[b] - b*CAP), scan -> bin_base
__global__ void k_scan_bins2(const unsigned* __restrict__ gcursor,
                             unsigned* __restrict__ bin_base, int nbin) {
    __shared__ unsigned sm[SBS];
    int t = threadIdx.x;
    int k = (nbin + SBS - 1) / SBS;
    int st = t * k, en = min(st + k, nbin);
    unsigned loc = 0;
    for (int i = st; i < en; i++) loc += gcursor[i] - (unsigned)i * CAP;
    sm[t] = loc;
    __syncthreads();
    for (int off = 1; off < SBS; off <<= 1) {
        unsigned x = (t >= off) ? sm[t - off] : 0u;
        __syncthreads();
        sm[t] += x;
        __syncthreads();
    }
    unsigned run = (t == 0) ? 0u : sm[t - 1];
    for (int i = st; i < en; i++) {
        bin_base[i] = run;
        run += gcursor[i] - (unsigned)i * CAP;
    }
    if (t == SBS - 1) bin_base[nbin] = run;
}

// level 2: block per bin, 1024 threads; per-a counts in LDS, scan, coalesced
// scat_base, L2-local compact pool_b scatter + tpos record (fixed-cap temp idx)
__global__ __launch_bounds__(1024)
void k_fine2(const unsigned* __restrict__ bin_base,
             const unsigned* __restrict__ temp_pk,
             unsigned* __restrict__ pool_b,
             unsigned* __restrict__ tpos,
             unsigned* __restrict__ scat_base, int N, int nbin) {
    __shared__ unsigned s_cnt[BIN_W];
    __shared__ unsigned s_scan[BIN_W];
    int bin = blockIdx.x;
    int tid = threadIdx.x;  // 0..1023
    int a0 = bin << BIN_SHIFT;
    int w = min(BIN_W, N - a0);
    unsigned start = bin_base[bin];
    unsigned cnt_bin = bin_base[bin + 1] - start;
    unsigned tstart = (unsigned)bin * CAP;
    s_cnt[tid] = 0;
    __syncthreads();
    for (unsigned i = tid; i < cnt_bin; i += 1024)
        atomicAdd(&s_cnt[temp_pk[tstart + i] >> 18], 1u);
    __syncthreads();
    unsigned c = s_cnt[tid];
    s_scan[tid] = c;
    __syncthreads();
    for (int off = 1; off < BIN_W; off <<= 1) {
        unsigned x = (tid >= off) ? s_scan[tid - off] : 0u;
        __syncthreads();
        s_scan[tid] += x;
        __syncthreads();
    }
    unsigned base = start + s_scan[tid] - c;  // exclusive
    if (tid < w) scat_base[a0 + tid] = base;
    s_cnt[tid] = base;                        // cursor
    if (bin == nbin - 1 && tid == 0) scat_base[N] = bin_base[nbin];
    __syncthreads();
    for (unsigned i = tid; i < cnt_bin; i += 1024) {
        unsigned idx = tstart + i;
        unsigned t = temp_pk[idx];
        unsigned pos = atomicAdd(&s_cnt[t >> 18], 1u);
        pool_b[pos] = t & M28;
        tpos[pos] = idx;   // pool pos -> fixed-cap temp idx
    }
}

// ---- element-parallel dedupe + rank ----

__device__ __forceinline__ int find_bin(const unsigned* __restrict__ bin_base,
                                        unsigned idx, int nbin) {
    int lo = 0, hi = nbin - 1;
    while (lo < hi) {
        int mid = (lo + hi + 1) >> 1;
        if (bin_base[mid] <= idx) lo = mid;
        else hi = mid - 1;
    }
    return lo;
}

// pass A: mark later duplicate occurrences (own-element write; readers mask)
__global__ void k_markdup(const unsigned* __restrict__ bin_base,
                          const unsigned* __restrict__ scat_base,
                          unsigned* __restrict__ pool_b, int nbin) {
    unsigned total = bin_base[nbin];
    unsigned idx = blockIdx.x * 256u + threadIdx.x;
    if (idx >= total) return;
    int bin = find_bin(bin_base, idx, nbin);
    unsigned p = pool_b[idx];
    unsigned a = ((unsigned)bin << BIN_SHIFT) + (p >> 18);
    unsigned s = scat_base[a];
    bool dup = false;
    for (unsigned j = s; j < idx; j++) {
        if ((pool_b[j] & M28) == p) { dup = true; break; }
    }
    if (dup) pool_b[idx] = p | DUPBIT;
}

// pass B: distinct-rank via span count. Writes:
//   rank8[tpos[idx]] = r   pool_sorted[s+r] = b (non-dups)   cnt[a] (span head)
__global__ void k_rankem(const unsigned* __restrict__ bin_base,
                         const unsigned* __restrict__ scat_base,
                         const unsigned* __restrict__ pool_b,
                         const unsigned* __restrict__ tpos,
                         unsigned* __restrict__ pool_sorted,
                         unsigned char* __restrict__ rank8,
                         unsigned* __restrict__ cnt, int nbin) {
    unsigned total = bin_base[nbin];
    unsigned idx = blockIdx.x * 256u + threadIdx.x;
    if (idx >= total) return;
    int bin = find_bin(bin_base, idx, nbin);
    unsigned p = pool_b[idx];
    unsigned pm = p & M28;
    unsigned a = ((unsigned)bin << BIN_SHIFT) + (pm >> 18);
    unsigned s = scat_base[a];
    unsigned e = scat_base[a + 1];
    int r = 0;
    for (unsigned j = s; j < e; j++) {
        unsigned q = pool_b[j];
        r += (!(q & DUPBIT) && (q & M28) < pm) ? 1 : 0;
    }
    rank8[tpos[idx]] = (unsigned char)r;
    if (!(p & DUPBIT)) pool_sorted[s + r] = pm & VMASK;  // b only
    if (idx == s) {
        int d = 0;
        for (unsigned j = s; j < e; j++) d += (pool_b[j] & DUPBIT) ? 0 : 1;
        cnt[a] = (unsigned)d;
    }
}

// wave-per-bucket vert writer
__global__ void k_verts(const float* __restrict__ pos, const float* __restrict__ sdf,
                        const unsigned* __restrict__ scat_base, const unsigned* __restrict__ cnt,
                        const unsigned* __restrict__ rank_base, const unsigned* __restrict__ pool_sorted,
                        float* __restrict__ verts, float* __restrict__ vvalid, int N) {
    int a = (int)((blockIdx.x * blockDim.x + threadIdx.x) >> 6);
    int lane = threadIdx.x & 63;
    if (a >= N) return;
    int d = (int)cnt[a];
    if (d == 0) return;
    unsigned s = scat_base[a];
    unsigned rb = rank_base[a];
    float sa = sdf[a];
    float pax = pos[(size_t)a * 3 + 0];
    float pay = pos[(size_t)a * 3 + 1];
    float paz = pos[(size_t)a * 3 + 2];
    for (int i = lane; i < d; i += 64) {
        unsigned b = pool_sorted[s + i];
        float sbv = sdf[b];
        float denom = sa - sbv;
        float w0 = (-sbv) / denom;
        float w1 = sa / denom;
        size_t r = (size_t)(rb + i);
        verts[r * 3 + 0] = pax * w0 + pos[(size_t)b * 3 + 0] * w1;
        verts[r * 3 + 1] = pay * w0 + pos[(size_t)b * 3 + 1] * w1;
        verts[r * 3 + 2] = paz * w0 + pos[(size_t)b * 3 + 2] * w1;
        vvalid[r] = 1.0f;
    }
}

// faces: rank = rank_base[A] + rank8[eidx[...]] (direct byte gather)
__global__ void k_faces(const int* __restrict__ tet, const unsigned char* __restrict__ tcode,
                        const unsigned* __restrict__ eidx,
                        const unsigned* __restrict__ rank_base,
                        const unsigned char* __restrict__ rank8,
                        float* __restrict__ faces, float* __restrict__ fvalid, int F) {
    int f = blockIdx.x * blockDim.x + threadIdx.x;
    if (f >= F) return;
    int code = tcode[f];
    int nt = c_ntri[code];
    size_t r0 = (size_t)f * 3;
    size_t r1 = ((size_t)F + f) * 3;
    if (nt == 0) {
        faces[r0 + 0] = -1.f; faces[r0 + 1] = -1.f; faces[r0 + 2] = -1.f;
        faces[r1 + 0] = -1.f; faces[r1 + 1] = -1.f; faces[r1 + 2] = -1.f;
        fvalid[f] = 0.f;
        fvalid[F + f] = 0.f;
        return;
    }
    int4 tv = ((const int4*)tet)[f];
    int v[4] = {tv.x, tv.y, tv.z, tv.w};
    float rk[6];
#pragma unroll
    for (int j = 0; j < 6; j++) {
        int i0 = c_ea[j], i1 = c_eb[j];
        if (((code >> i0) & 1) != ((code >> i1) & 1)) {
            int A = min(v[i0], v[i1]);
            rk[j] = (float)(rank_base[A] + (unsigned)rank8[eidx[f * 6 + j]]);
        }
    }
    float f0[3], f1[3] = {-1.f, -1.f, -1.f};
#pragma unroll
    for (int k = 0; k < 3; k++) f0[k] = rk[c_tri[code][k]];
    if (nt == 2) {
#pragma unroll
        for (int k = 0; k < 3; k++) f1[k] = rk[c_tri[code][3 + k]];
    }
    faces[r0 + 0] = f0[0]; faces[r0 + 1] = f0[1]; faces[r0 + 2] = f0[2];
    faces[r1 + 0] = f1[0]; faces[r1 + 1] = f1[1]; faces[r1 + 2] = f1[2];
    fvalid[f] = 1.f;
    fvalid[F + f] = (nt == 2) ? 1.f : 0.f;
}

// ---------------- host launch ----------------
static void run_scan(const unsigned* in, unsigned* out, unsigned* bsum,
                     int n, hipStream_t stream) {
    int nb = (n + SBS * SIT - 1) / (SBS * SIT);
    k_scan1<<<nb, SBS, 0, stream>>>(in, out, bsum, n);
    k_scan2<<<1, SBS, 0, stream>>>(bsum, out, nb, n);
    k_scan3<<<nb, SBS, 0, stream>>>(out, bsum, n);
}

extern "C" void kernel_launch(void* const* d_in, const int* in_sizes, int n_in,
                              void* d_out, int out_size, void* d_ws, size_t ws_size,
                              hipStream_t stream) {
    const float* pos = (const float*)d_in[0];
    const float* sdf = (const float*)d_in[1];
    const int* tet = (const int*)d_in[2];
    const int N = in_sizes[1];
    const int F = in_sizes[2] / 4;
    const int E = F * 6;
    const int nbin = (N + BIN_W - 1) >> BIN_SHIFT;
    const size_t tempw = (size_t)nbin * CAP;

    float* out = (float*)d_out;
    size_t nverts = (size_t)6 * F;
    size_t nfaces = (size_t)2 * F;
    float* o_verts = out;                    // [6F,3]
    float* o_faces = out + nverts * 3;       // [2F,3]
    float* o_vvalid = o_faces + nfaces * 3;  // [6F]
    float* o_fvalid = o_vvalid + nverts;     // [2F]

    unsigned* w = (unsigned*)d_ws;
    unsigned* scat_base = w;                  // N+1
    unsigned* cnt = scat_base + N + 1;        // N (zeroed)
    unsigned* rank_base = cnt + N;            // N+1
    unsigned* bsum = rank_base + N + 1;       // 4096
    unsigned* bin_base = bsum + 4096;         // MAXBIN+1
    unsigned* gcursor = bin_base + MAXBIN + 1;// MAXBIN
    unsigned* pool_b = gcursor + MAXBIN;      // E
    unsigned* pool_sorted = pool_b + E;       // E
    unsigned* eidx = pool_sorted + E;         // E
    unsigned* tpos = eidx + E;                // E
    unsigned* temp_pk = tpos + E;             // nbin*CAP
    unsigned char* rank8 = (unsigned char*)(temp_pk + tempw);  // nbin*CAP bytes
    unsigned char* tcode = rank8 + tempw;                      // F bytes

    const int BS = 256;
    int gF = (F + BS - 1) / BS;
    int gW = (N + 3) / 4;        // wave-per-bucket blocks (k_verts)
    int gE = (E + BS - 1) / BS;  // element-parallel blocks (upper bound)
    int gV = (int)((nverts + BS - 1) / BS);
    int gB = (F + BS * 4 - 1) / (BS * 4);

    // 1. zero cnt; init fixed-cap cursors
    k_zero_u32<<<(N + BS - 1) / BS, BS, 0, stream>>>(cnt, N);
    k_init_cursor<<<(nbin + BS - 1) / BS, BS, 0, stream>>>(gcursor, nbin);

    // 2. single-pass tcode + binned scatter (fixed-cap regions)
    k_binscatter2<<<gB, BS, 0, stream>>>(tet, sdf, tcode, gcursor, temp_pk, eidx, F, nbin);

    // 3. counts from cursors -> bin_base
    k_scan_bins2<<<1, SBS, 0, stream>>>(gcursor, bin_base, nbin);

    // 4. fine scatter -> compact pool + scat_base + tpos
    k_fine2<<<nbin, 1024, 0, stream>>>(bin_base, temp_pk, pool_b, tpos, scat_base, N, nbin);

    // 5. element-parallel dedupe + rank
    k_markdup<<<gE, BS, 0, stream>>>(bin_base, scat_base, pool_b, nbin);
    k_rankem<<<gE, BS, 0, stream>>>(bin_base, scat_base, pool_b, tpos,
                                    pool_sorted, rank8, cnt, nbin);

    // 6. scan distinct counts -> global vert ranks
    run_scan(cnt, rank_base, bsum, N, stream);

    // 7. zero only padded vert rows
    k_zero_pad<<<gV, BS, 0, stream>>>(rank_base + N, o_verts, o_vvalid, (int)nverts);

    // 8. verts
    k_verts<<<gW, BS, 0, stream>>>(pos, sdf, scat_base, cnt, rank_base, pool_sorted,
                                   o_verts, o_vvalid, N);

    // 9. faces
    k_faces<<<gF, BS, 0, stream>>>(tet, tcode, eidx, rank_base, rank8,
                                   o_faces, o_fvalid, F);
}